// Round 8
// baseline (114.945 us; speedup 1.0000x reference)
//
#include <hip/hip_runtime.h>
#include <math.h>

// MVAE forward, persistent kernel, round 8 = round 5 (PROVEN, absmax 0.0)
// + ONE bisected change: Phase A (enc0/enc1/enc2/mu/lv/z) computed
// REDUNDANTLY per WG -> grid barriers 1-4 of round 5 eliminated (4 remain).
// Phase A uses ONLY plain __syncthreads() (full drain, proven), distinct LDS
// buffers, and the proven full-wave dot4+wred row pattern.
// All cross-WG mechanisms verbatim round 5: entry global_load_lds staging,
// cstore(sc1) activation writes, copy_act(gll16) activation reads, gridbar.

#define NWG   64
#define BLOCK 256

__device__ __align__(128) float g_g0[256];
__device__ __align__(128) float g_g1[256];
__device__ __align__(128) float g_g2[256];
__device__ __align__(128) float g_gates[32];
__device__ __align__(128) float g_h0[1536];
__device__ __align__(128) float g_h1[1536];
__device__ __align__(128) float g_h2[1536];
__device__ __align__(128) float g_oute[384];

struct P {
  const float *prev, *curr, *eps;
  const float *ew0,*eb0,*ew1,*eb1,*ew2,*eb2;
  const float *muw,*mub,*lvw,*lvb;
  const float *gw0,*gb0,*gw1,*gb1,*gw2,*gb2,*gw3,*gb3;
  const float *xw0,*xb0,*xw1,*xb1,*xw2,*xb2,*xw3,*xb3;
  float* out;
};

__device__ __forceinline__ float cload(const float* a) {
  int v = __hip_atomic_load((const int*)a, __ATOMIC_RELAXED,
                            __HIP_MEMORY_SCOPE_AGENT);
  return __int_as_float(v);
}
__device__ __forceinline__ void cstore(float* a, float v) {
  __hip_atomic_store((int*)a, __float_as_int(v), __ATOMIC_RELAXED,
                     __HIP_MEMORY_SCOPE_AGENT);
}

__device__ __forceinline__ void gll16(const void* g, void* l) {
  __builtin_amdgcn_global_load_lds((const __attribute__((address_space(1))) void*)g,
                                   (__attribute__((address_space(3))) void*)l,
                                   16, 0, 0);
}
__device__ __forceinline__ void gll4(const void* g, void* l) {
  __builtin_amdgcn_global_load_lds((const __attribute__((address_space(1))) void*)g,
                                   (__attribute__((address_space(3))) void*)l,
                                   4, 0, 0);
}

__device__ __forceinline__ float wred(float v) {
#pragma unroll
  for (int m = 32; m; m >>= 1) v += __shfl_xor(v, m, 64);
  return v;
}
__device__ __forceinline__ float elu(float x) { return x > 0.f ? x : expm1f(x); }
__device__ __forceinline__ float dot4(float4 a, float4 b) {
  return a.x*b.x + a.y*b.y + a.z*b.z + a.w*b.w;
}

__device__ __forceinline__ void gridbar(int* flags, int phase) {
  __syncthreads();                 // vmcnt(0) drain: sc1 stores ack'd at MALL
  if (threadIdx.x == 0)
    __hip_atomic_store(&flags[blockIdx.x * 16], phase,
                       __ATOMIC_RELAXED, __HIP_MEMORY_SCOPE_AGENT);
  if (threadIdx.x < NWG) {
    while (__hip_atomic_load(&flags[threadIdx.x * 16],
                             __ATOMIC_RELAXED, __HIP_MEMORY_SCOPE_AGENT) < phase)
      __builtin_amdgcn_s_sleep(1);
  }
  __syncthreads();
}

// stage gate(256f)+expert(1536f) activations into LDS: 7 x 1KB wave-instrs
__device__ __forceinline__ void copy_act(const float* gg, const float* gh,
                                         float* sg, float* sh,
                                         int wvin, int lane) {
  if (wvin == 0) { gll16(gh +        lane*4, sh);
                   gll16(gh + 1024 + lane*4, sh + 1024); }
  if (wvin == 1) { gll16(gh +  256 + lane*4, sh +  256);
                   gll16(gh + 1280 + lane*4, sh + 1280); }
  if (wvin == 2) { gll16(gh +  512 + lane*4, sh +  512);
                   gll16(gg +        lane*4, sg); }
  if (wvin == 3) { gll16(gh +  768 + lane*4, sh +  768); }
}

__global__ __launch_bounds__(BLOCK, 1) void mvae_main(P p, int* flags) {
  const int tid  = threadIdx.x;
  const int lane = tid & 63;
  const int wvin = tid >> 6;                // 0..3
  const int W    = blockIdx.x * 4 + wvin;   // 0..255

  __shared__ __align__(16) float s_w4[4][7][96];
  __shared__ __align__(16) float s_w5[4][7][288];
  __shared__ __align__(16) float s_w6[4][7][288];
  __shared__ __align__(16) float s_w7[4][2][288];
  __shared__ __align__(16) float s_g[256];
  __shared__ __align__(16) float s_h[1536];
  __shared__ __align__(16) float s_x[128];    // [prev|curr] (124)
  __shared__ __align__(16) float s_a0[256];
  __shared__ __align__(16) float s_a1[256];
  __shared__ __align__(16) float s_a2[256];
  __shared__ __align__(16) float s_zp[96];    // [z(32) | prev(62)]
  __shared__ float s_ml[64];                  // mu | lv
  __shared__ float s_o[384];
  __shared__ float s_gg[8];

  // ---- entry: tiny inputs into LDS ----
  if (tid < 124) s_x[tid] = (tid < 62) ? p.prev[tid] : p.curr[tid - 62];
  if (tid < 62)  s_zp[32 + tid] = p.prev[tid];

  // ================= ENTRY STAGING (round-5 verbatim, minus enc rows) =====
#pragma unroll
  for (int k = 0; k < 7; ++k) {            // S4: rows W+256k, 94 floats
    int r = W + 256 * k;
    const float* src = (r < 256) ? p.gw0 + r * 94 : p.xw0 + (r - 256) * 94;
    float* dst = s_w4[wvin][k];
    if (lane < 23)       gll16(src + lane * 4, dst);
    else if (lane == 23) { gll4(src + 92, dst + 69);    // -> float 92
                           gll4(src + 93, dst + 70); }  // -> float 93
  }
#pragma unroll
  for (int k = 0; k < 7; ++k) {            // S5
    int r = W + 256 * k;
    float* dst = s_w5[wvin][k];
    if (r < 256) gll16(p.gw1 + r * 256 + lane * 4, dst);
    else {
      const float* src = p.xw1 + (r - 256) * 288;
      gll16(src + lane * 4, dst);
      if (lane < 8) gll16(src + 256 + lane * 4, dst + 256);
    }
  }
#pragma unroll
  for (int k = 0; k < 7; ++k) {            // S6
    int r = W + 256 * k;
    float* dst = s_w6[wvin][k];
    if (r < 256) gll16(p.gw2 + r * 256 + lane * 4, dst);
    else {
      const float* src = p.xw2 + (r - 256) * 288;
      gll16(src + lane * 4, dst);
      if (lane < 8) gll16(src + 256 + lane * 4, dst + 256);
    }
  }
  {                                        // S7 row A
    float* dst = s_w7[wvin][0];
    if (W < 6) gll16(p.gw3 + W * 256 + lane * 4, dst);
    else {
      const float* src = p.xw3 + (W - 6) * 288;
      gll16(src + lane * 4, dst);
      if (lane < 8) gll16(src + 256 + lane * 4, dst + 256);
    }
  }
  if (W < 122) {                           // S7 row B
    float* dst = s_w7[wvin][1];
    const float* src = p.xw3 + (W + 250) * 288;
    gll16(src + lane * 4, dst);
    if (lane < 8) gll16(src + 256 + lane * 4, dst + 256);
  }

  __syncthreads();   // drains staging (vmcnt 0); s_x/s_zp visible

  // ================= PHASE A: redundant per-WG encoder ====================
  // enc0: 64 rows/wave, full-wave dot (lanes 0..30 hold float4 of 124)
  {
    float4 x0 = make_float4(0.f, 0.f, 0.f, 0.f);
    if (lane < 31) x0 = *(const float4*)(s_x + 4 * lane);
    for (int i = 0; i < 64; ++i) {
      int r = (wvin << 6) | i;
      float4 w = make_float4(0.f, 0.f, 0.f, 0.f);
      if (lane < 31) w = *(const float4*)(p.ew0 + r * 124 + 4 * lane);
      float s = wred(dot4(w, x0));
      if (!lane) s_a0[r] = elu(s + p.eb0[r]);
    }
  }
  __syncthreads();

  // enc1
  {
    float4 x = *(const float4*)(s_a0 + 4 * lane);
    for (int i = 0; i < 64; ++i) {
      int r = (wvin << 6) | i;
      float4 w = *(const float4*)(p.ew1 + r * 256 + 4 * lane);
      float s = wred(dot4(w, x));
      if (!lane) s_a1[r] = elu(s + p.eb1[r]);
    }
  }
  __syncthreads();

  // enc2
  {
    float4 x = *(const float4*)(s_a1 + 4 * lane);
    for (int i = 0; i < 64; ++i) {
      int r = (wvin << 6) | i;
      float4 w = *(const float4*)(p.ew2 + r * 256 + 4 * lane);
      float s = wred(dot4(w, x));
      if (!lane) s_a2[r] = elu(s + p.eb2[r]);
    }
  }
  __syncthreads();

  // mu / lv: 16 rows/wave
  {
    float4 x = *(const float4*)(s_a2 + 4 * lane);
    for (int i = 0; i < 16; ++i) {
      int row = (wvin << 4) | i;            // 0..31 mu, 32..63 lv
      const float* wr = (row < 32) ? p.muw + row * 256
                                   : p.lvw + (row - 32) * 256;
      float4 w = *(const float4*)(wr + 4 * lane);
      float s = wred(dot4(w, x));
      if (!lane)
        s_ml[row] = s + ((row < 32) ? p.mub[row] : p.lvb[row - 32]);
    }
  }
  __syncthreads();

  // z (WG0 also writes mu/logvar outputs)
  if (tid < 32) {
    float mu = s_ml[tid], lv = s_ml[32 + tid];
    s_zp[tid] = mu + p.eps[tid] * expf(0.5f * lv);
    if (blockIdx.x == 0) { p.out[62 + tid] = mu; p.out[94 + tid] = lv; }
  }
  __syncthreads();

  // ================= S4: gate0 + expert h0 (x=[z|prev], 94) ===============
  {
    float xa = s_zp[lane];
    float xb = (lane < 30) ? s_zp[64 + lane] : 0.f;
#pragma unroll
    for (int k = 0; k < 7; ++k) {
      int r = W + 256 * k;
      const float* wrow = s_w4[wvin][k];
      float wb = (lane < 30) ? wrow[64 + lane] : 0.f;
      float s = wred(wrow[lane] * xa + wb * xb);
      if (!lane) {
        if (r < 256) cstore(&g_g0[r], elu(s + p.gb0[r]));
        else         cstore(&g_h0[r - 256], elu(s + p.xb0[r - 256]));
      }
    }
  }
  gridbar(flags, 1);

  // ================= S5: gate1 + expert h1 ================================
  copy_act(g_g0, g_h0, s_g, s_h, wvin, lane);
  __syncthreads();
  {
    float4 xg = *(const float4*)(s_g + 4 * lane);
    float4 xz4 = make_float4(0.f, 0.f, 0.f, 0.f);
    if (lane < 8) xz4 = *(const float4*)(s_zp + 4 * lane);
#pragma unroll
    for (int k = 0; k < 7; ++k) {
      int r = W + 256 * k;
      const float* wrow = s_w5[wvin][k];
      float4 w = *(const float4*)(wrow + 4 * lane);
      if (r < 256) {
        float s = wred(dot4(w, xg));
        if (!lane) cstore(&g_g1[r], elu(s + p.gb1[r]));
      } else {
        int q = r - 256, e = q >> 8;
        float4 xh = xz4;
        if (lane >= 8) xh = *(const float4*)(s_h + e * 256 + 4 * lane - 32);
        float s = dot4(w, xh);
        if (lane < 32) s += wrow[256 + lane] * s_h[e * 256 + 224 + lane];
        s = wred(s);
        if (!lane) cstore(&g_h1[q], elu(s + p.xb1[q]));
      }
    }
  }
  gridbar(flags, 2);

  // ================= S6: gate2 + expert h2 ================================
  copy_act(g_g1, g_h1, s_g, s_h, wvin, lane);
  __syncthreads();
  {
    float4 xg = *(const float4*)(s_g + 4 * lane);
    float4 xz4 = make_float4(0.f, 0.f, 0.f, 0.f);
    if (lane < 8) xz4 = *(const float4*)(s_zp + 4 * lane);
#pragma unroll
    for (int k = 0; k < 7; ++k) {
      int r = W + 256 * k;
      const float* wrow = s_w6[wvin][k];
      float4 w = *(const float4*)(wrow + 4 * lane);
      if (r < 256) {
        float s = wred(dot4(w, xg));
        if (!lane) cstore(&g_g2[r], elu(s + p.gb2[r]));
      } else {
        int q = r - 256, e = q >> 8;
        float4 xh = xz4;
        if (lane >= 8) xh = *(const float4*)(s_h + e * 256 + 4 * lane - 32);
        float s = dot4(w, xh);
        if (lane < 32) s += wrow[256 + lane] * s_h[e * 256 + 224 + lane];
        s = wred(s);
        if (!lane) cstore(&g_h2[q], elu(s + p.xb2[q]));
      }
    }
  }
  gridbar(flags, 3);

  // ================= S7: gate3 logits + out_e =============================
  copy_act(g_g2, g_h2, s_g, s_h, wvin, lane);
  __syncthreads();
  {
    const float* wrow = s_w7[wvin][0];
    float4 w = *(const float4*)(wrow + 4 * lane);
    if (W < 6) {
      float4 x = *(const float4*)(s_g + 4 * lane);
      float s = wred(dot4(w, x));
      if (!lane) cstore(&g_gates[W], s + p.gb3[W]);    // raw logits
    } else {
      int q = W - 6, e = q / 62;
      float4 xh = make_float4(0.f, 0.f, 0.f, 0.f);
      if (lane < 8) xh = *(const float4*)(s_zp + 4 * lane);
      else          xh = *(const float4*)(s_h + e * 256 + 4 * lane - 32);
      float s = dot4(w, xh);
      if (lane < 32) s += wrow[256 + lane] * s_h[e * 256 + 224 + lane];
      s = wred(s);
      if (!lane) cstore(&g_oute[q], s + p.xb3[q]);
    }
  }
  if (W < 122) {
    const float* wrow = s_w7[wvin][1];
    float4 w = *(const float4*)(wrow + 4 * lane);
    int q = W + 250, e = q / 62;
    float4 xh = make_float4(0.f, 0.f, 0.f, 0.f);
    if (lane < 8) xh = *(const float4*)(s_zp + 4 * lane);
    else          xh = *(const float4*)(s_h + e * 256 + 4 * lane - 32);
    float s = dot4(w, xh);
    if (lane < 32) s += wrow[256 + lane] * s_h[e * 256 + 224 + lane];
    s = wred(s);
    if (!lane) cstore(&g_oute[q], s + p.xb3[q]);
  }
  gridbar(flags, 4);

  // ================= S8: decoded (WG0, parallel sc1 reads) ================
  if (blockIdx.x == 0) {
    s_o[tid] = cload(&g_oute[tid]);
    if (tid < 116) s_o[tid + 256] = cload(&g_oute[tid + 256]);
    if (tid < 6)   s_gg[tid] = cload(&g_gates[tid]);
    __syncthreads();
    if (tid < 62) {
      float s = 0.f;
#pragma unroll
      for (int e = 0; e < 6; ++e) s += s_o[e * 62 + tid] * s_gg[e];
      p.out[tid] = s;
    }
  }
}

extern "C" void kernel_launch(void* const* d_in, const int* in_sizes, int n_in,
                              void* d_out, int out_size, void* d_ws, size_t ws_size,
                              hipStream_t stream) {
  (void)in_sizes; (void)n_in; (void)out_size; (void)ws_size;
  const float* const* in = (const float* const*)d_in;
  P p;
  p.prev = in[0];  p.curr = in[1];  p.eps = in[2];
  p.ew0 = in[3];   p.eb0 = in[4];   p.ew1 = in[5];  p.eb1 = in[6];
  p.ew2 = in[7];   p.eb2 = in[8];
  p.muw = in[9];   p.mub = in[10];  p.lvw = in[11]; p.lvb = in[12];
  p.gw0 = in[13];  p.gb0 = in[14];  p.gw1 = in[15]; p.gb1 = in[16];
  p.gw2 = in[17];  p.gb2 = in[18];  p.gw3 = in[19]; p.gb3 = in[20];
  p.xw0 = in[21];  p.xb0 = in[22];  p.xw1 = in[23]; p.xb1 = in[24];
  p.xw2 = in[25];  p.xb2 = in[26];  p.xw3 = in[27]; p.xb3 = in[28];
  p.out = (float*)d_out;

  int* flags = (int*)d_ws;                        // 64 WGs x 1 cacheline
  hipMemsetAsync(flags, 0, NWG * 16 * sizeof(int), stream);
  mvae_main<<<NWG, BLOCK, 0, stream>>>(p, flags);
}

// Round 10
// 51.735 us; speedup vs baseline: 2.2218x; 2.2218x over previous
//
#include <hip/hip_runtime.h>
#include <math.h>

// MVAE forward, persistent kernel, round 10 — STRICT BISECT.
// = round 8 VERBATIM (passed, absmax 0.0: 4 grid barriers, S7 rows A/B via
//   cstore to g_oute/g_gates, WG0 S8 tail via cload)
// + ONE change: Phase A swapped to round-9's row-per-lane serial-K form
//   (per-lane affine float4 loads, unroll 16, no wred chains; split-K mu/lv).
// Purpose: isolate whether row-per-lane Phase A or the S7' merge caused
// round 9's failure. Phase A reads only read-only weights + LDS.

#define NWG   64
#define BLOCK 256

__device__ __align__(128) float g_g0[256];
__device__ __align__(128) float g_g1[256];
__device__ __align__(128) float g_g2[256];
__device__ __align__(128) float g_gates[32];
__device__ __align__(128) float g_h0[1536];
__device__ __align__(128) float g_h1[1536];
__device__ __align__(128) float g_h2[1536];
__device__ __align__(128) float g_oute[384];

struct P {
  const float *prev, *curr, *eps;
  const float *ew0,*eb0,*ew1,*eb1,*ew2,*eb2;
  const float *muw,*mub,*lvw,*lvb;
  const float *gw0,*gb0,*gw1,*gb1,*gw2,*gb2,*gw3,*gb3;
  const float *xw0,*xb0,*xw1,*xb1,*xw2,*xb2,*xw3,*xb3;
  float* out;
};

__device__ __forceinline__ float cload(const float* a) {
  int v = __hip_atomic_load((const int*)a, __ATOMIC_RELAXED,
                            __HIP_MEMORY_SCOPE_AGENT);
  return __int_as_float(v);
}
__device__ __forceinline__ void cstore(float* a, float v) {
  __hip_atomic_store((int*)a, __float_as_int(v), __ATOMIC_RELAXED,
                     __HIP_MEMORY_SCOPE_AGENT);
}

__device__ __forceinline__ void gll16(const void* g, void* l) {
  __builtin_amdgcn_global_load_lds((const __attribute__((address_space(1))) void*)g,
                                   (__attribute__((address_space(3))) void*)l,
                                   16, 0, 0);
}
__device__ __forceinline__ void gll4(const void* g, void* l) {
  __builtin_amdgcn_global_load_lds((const __attribute__((address_space(1))) void*)g,
                                   (__attribute__((address_space(3))) void*)l,
                                   4, 0, 0);
}

__device__ __forceinline__ float wred(float v) {
#pragma unroll
  for (int m = 32; m; m >>= 1) v += __shfl_xor(v, m, 64);
  return v;
}
__device__ __forceinline__ float elu(float x) { return x > 0.f ? x : expm1f(x); }
__device__ __forceinline__ float dot4(float4 a, float4 b) {
  return a.x*b.x + a.y*b.y + a.z*b.z + a.w*b.w;
}

__device__ __forceinline__ void gridbar(int* flags, int phase) {
  __syncthreads();                 // vmcnt(0) drain: sc1 stores ack'd at MALL
  if (threadIdx.x == 0)
    __hip_atomic_store(&flags[blockIdx.x * 16], phase,
                       __ATOMIC_RELAXED, __HIP_MEMORY_SCOPE_AGENT);
  if (threadIdx.x < NWG) {
    while (__hip_atomic_load(&flags[threadIdx.x * 16],
                             __ATOMIC_RELAXED, __HIP_MEMORY_SCOPE_AGENT) < phase)
      __builtin_amdgcn_s_sleep(1);
  }
  __syncthreads();
}

// stage gate(256f)+expert(1536f) activations into LDS: 7 x 1KB wave-instrs
__device__ __forceinline__ void copy_act(const float* gg, const float* gh,
                                         float* sg, float* sh,
                                         int wvin, int lane) {
  if (wvin == 0) { gll16(gh +        lane*4, sh);
                   gll16(gh + 1024 + lane*4, sh + 1024); }
  if (wvin == 1) { gll16(gh +  256 + lane*4, sh +  256);
                   gll16(gh + 1280 + lane*4, sh + 1280); }
  if (wvin == 2) { gll16(gh +  512 + lane*4, sh +  512);
                   gll16(gg +        lane*4, sg); }
  if (wvin == 3) { gll16(gh +  768 + lane*4, sh +  768); }
}

__global__ __launch_bounds__(BLOCK, 1) void mvae_main(P p, int* flags) {
  const int tid  = threadIdx.x;
  const int lane = tid & 63;
  const int wvin = tid >> 6;                // 0..3
  const int W    = blockIdx.x * 4 + wvin;   // 0..255

  __shared__ __align__(16) float s_w4[4][7][96];
  __shared__ __align__(16) float s_w5[4][7][288];
  __shared__ __align__(16) float s_w6[4][7][288];
  __shared__ __align__(16) float s_w7[4][2][288];
  __shared__ __align__(16) float s_g[256];
  __shared__ __align__(16) float s_h[1536];
  __shared__ __align__(16) float s_x[128];    // [prev|curr] (124)
  __shared__ __align__(16) float s_a0[256];
  __shared__ __align__(16) float s_a1[256];
  __shared__ __align__(16) float s_a2[256];
  __shared__ __align__(16) float s_zp[96];    // [z(32) | prev(62)]
  __shared__ float s_ml[64];                  // mu | lv
  __shared__ float s_pml[4][64];              // split-K partials
  __shared__ float s_o[384];
  __shared__ float s_gg[8];

  // ---- entry: tiny inputs into LDS ----
  if (tid < 124) s_x[tid] = (tid < 62) ? p.prev[tid] : p.curr[tid - 62];
  if (tid < 62)  s_zp[32 + tid] = p.prev[tid];

  // ================= ENTRY STAGING (round-8 verbatim) =====================
#pragma unroll
  for (int k = 0; k < 7; ++k) {            // S4: rows W+256k, 94 floats
    int r = W + 256 * k;
    const float* src = (r < 256) ? p.gw0 + r * 94 : p.xw0 + (r - 256) * 94;
    float* dst = s_w4[wvin][k];
    if (lane < 23)       gll16(src + lane * 4, dst);
    else if (lane == 23) { gll4(src + 92, dst + 69);    // -> float 92
                           gll4(src + 93, dst + 70); }  // -> float 93
  }
#pragma unroll
  for (int k = 0; k < 7; ++k) {            // S5
    int r = W + 256 * k;
    float* dst = s_w5[wvin][k];
    if (r < 256) gll16(p.gw1 + r * 256 + lane * 4, dst);
    else {
      const float* src = p.xw1 + (r - 256) * 288;
      gll16(src + lane * 4, dst);
      if (lane < 8) gll16(src + 256 + lane * 4, dst + 256);
    }
  }
#pragma unroll
  for (int k = 0; k < 7; ++k) {            // S6
    int r = W + 256 * k;
    float* dst = s_w6[wvin][k];
    if (r < 256) gll16(p.gw2 + r * 256 + lane * 4, dst);
    else {
      const float* src = p.xw2 + (r - 256) * 288;
      gll16(src + lane * 4, dst);
      if (lane < 8) gll16(src + 256 + lane * 4, dst + 256);
    }
  }
  {                                        // S7 row A
    float* dst = s_w7[wvin][0];
    if (W < 6) gll16(p.gw3 + W * 256 + lane * 4, dst);
    else {
      const float* src = p.xw3 + (W - 6) * 288;
      gll16(src + lane * 4, dst);
      if (lane < 8) gll16(src + 256 + lane * 4, dst + 256);
    }
  }
  if (W < 122) {                           // S7 row B
    float* dst = s_w7[wvin][1];
    const float* src = p.xw3 + (W + 250) * 288;
    gll16(src + lane * 4, dst);
    if (lane < 8) gll16(src + 256 + lane * 4, dst + 256);
  }

  __syncthreads();   // drains staging (vmcnt 0); s_x/s_zp visible

  // ========== PHASE A (round-9 form, UNDER TEST): row-per-lane ============
  // enc0: lane tid owns row tid; 31 float4, fully unrolled
  {
    const float* wr = p.ew0 + tid * 124;
    float acc[4] = {0.f, 0.f, 0.f, 0.f};
#pragma unroll
    for (int j = 0; j < 31; ++j)
      acc[j & 3] += dot4(*(const float4*)(wr + 4 * j),
                         *(const float4*)(s_x + 4 * j));
    s_a0[tid] = elu((acc[0] + acc[1]) + (acc[2] + acc[3]) + p.eb0[tid]);
  }
  __syncthreads();

  // enc1: row tid, 64 float4, unroll 16
  {
    const float* wr = p.ew1 + tid * 256;
    float acc[4] = {0.f, 0.f, 0.f, 0.f};
#pragma unroll 16
    for (int j = 0; j < 64; ++j)
      acc[j & 3] += dot4(*(const float4*)(wr + 4 * j),
                         *(const float4*)(s_a0 + 4 * j));
    s_a1[tid] = elu((acc[0] + acc[1]) + (acc[2] + acc[3]) + p.eb1[tid]);
  }
  __syncthreads();

  // enc2
  {
    const float* wr = p.ew2 + tid * 256;
    float acc[4] = {0.f, 0.f, 0.f, 0.f};
#pragma unroll 16
    for (int j = 0; j < 64; ++j)
      acc[j & 3] += dot4(*(const float4*)(wr + 4 * j),
                         *(const float4*)(s_a1 + 4 * j));
    s_a2[tid] = elu((acc[0] + acc[1]) + (acc[2] + acc[3]) + p.eb2[tid]);
  }
  __syncthreads();

  // mu/lv: 64 rows; split-K across the 4 waves, combine via LDS
  {
    int r = lane;                           // 0..31 mu rows, 32..63 lv rows
    const float* wr = ((r < 32) ? p.muw + r * 256
                                : p.lvw + (r - 32) * 256) + wvin * 64;
    const float* xr = s_a2 + wvin * 64;
    float acc[2] = {0.f, 0.f};
#pragma unroll
    for (int j = 0; j < 16; ++j)
      acc[j & 1] += dot4(*(const float4*)(wr + 4 * j),
                         *(const float4*)(xr + 4 * j));
    s_pml[wvin][lane] = acc[0] + acc[1];
  }
  __syncthreads();
  if (tid < 64) {
    float v = s_pml[0][tid] + s_pml[1][tid] + s_pml[2][tid] + s_pml[3][tid];
    s_ml[tid] = v + ((tid < 32) ? p.mub[tid] : p.lvb[tid - 32]);
  }
  __syncthreads();
  if (tid < 32) {
    float mu = s_ml[tid], lv = s_ml[32 + tid];
    s_zp[tid] = mu + p.eps[tid] * expf(0.5f * lv);
    if (blockIdx.x == 0) { p.out[62 + tid] = mu; p.out[94 + tid] = lv; }
  }
  __syncthreads();

  // ================= S4: gate0 + expert h0 (x=[z|prev], 94) ===============
  {
    float xa = s_zp[lane];
    float xb = (lane < 30) ? s_zp[64 + lane] : 0.f;
#pragma unroll
    for (int k = 0; k < 7; ++k) {
      int r = W + 256 * k;
      const float* wrow = s_w4[wvin][k];
      float wb = (lane < 30) ? wrow[64 + lane] : 0.f;
      float s = wred(wrow[lane] * xa + wb * xb);
      if (!lane) {
        if (r < 256) cstore(&g_g0[r], elu(s + p.gb0[r]));
        else         cstore(&g_h0[r - 256], elu(s + p.xb0[r - 256]));
      }
    }
  }
  gridbar(flags, 1);

  // ================= S5: gate1 + expert h1 ================================
  copy_act(g_g0, g_h0, s_g, s_h, wvin, lane);
  __syncthreads();
  {
    float4 xg = *(const float4*)(s_g + 4 * lane);
    float4 xz4 = make_float4(0.f, 0.f, 0.f, 0.f);
    if (lane < 8) xz4 = *(const float4*)(s_zp + 4 * lane);
#pragma unroll
    for (int k = 0; k < 7; ++k) {
      int r = W + 256 * k;
      const float* wrow = s_w5[wvin][k];
      float4 w = *(const float4*)(wrow + 4 * lane);
      if (r < 256) {
        float s = wred(dot4(w, xg));
        if (!lane) cstore(&g_g1[r], elu(s + p.gb1[r]));
      } else {
        int q = r - 256, e = q >> 8;
        float4 xh = xz4;
        if (lane >= 8) xh = *(const float4*)(s_h + e * 256 + 4 * lane - 32);
        float s = dot4(w, xh);
        if (lane < 32) s += wrow[256 + lane] * s_h[e * 256 + 224 + lane];
        s = wred(s);
        if (!lane) cstore(&g_h1[q], elu(s + p.xb1[q]));
      }
    }
  }
  gridbar(flags, 2);

  // ================= S6: gate2 + expert h2 ================================
  copy_act(g_g1, g_h1, s_g, s_h, wvin, lane);
  __syncthreads();
  {
    float4 xg = *(const float4*)(s_g + 4 * lane);
    float4 xz4 = make_float4(0.f, 0.f, 0.f, 0.f);
    if (lane < 8) xz4 = *(const float4*)(s_zp + 4 * lane);
#pragma unroll
    for (int k = 0; k < 7; ++k) {
      int r = W + 256 * k;
      const float* wrow = s_w6[wvin][k];
      float4 w = *(const float4*)(wrow + 4 * lane);
      if (r < 256) {
        float s = wred(dot4(w, xg));
        if (!lane) cstore(&g_g2[r], elu(s + p.gb2[r]));
      } else {
        int q = r - 256, e = q >> 8;
        float4 xh = xz4;
        if (lane >= 8) xh = *(const float4*)(s_h + e * 256 + 4 * lane - 32);
        float s = dot4(w, xh);
        if (lane < 32) s += wrow[256 + lane] * s_h[e * 256 + 224 + lane];
        s = wred(s);
        if (!lane) cstore(&g_h2[q], elu(s + p.xb2[q]));
      }
    }
  }
  gridbar(flags, 3);

  // ================= S7: gate3 logits + out_e (round-8 verbatim) ==========
  copy_act(g_g2, g_h2, s_g, s_h, wvin, lane);
  __syncthreads();
  {
    const float* wrow = s_w7[wvin][0];
    float4 w = *(const float4*)(wrow + 4 * lane);
    if (W < 6) {
      float4 x = *(const float4*)(s_g + 4 * lane);
      float s = wred(dot4(w, x));
      if (!lane) cstore(&g_gates[W], s + p.gb3[W]);    // raw logits
    } else {
      int q = W - 6, e = q / 62;
      float4 xh = make_float4(0.f, 0.f, 0.f, 0.f);
      if (lane < 8) xh = *(const float4*)(s_zp + 4 * lane);
      else          xh = *(const float4*)(s_h + e * 256 + 4 * lane - 32);
      float s = dot4(w, xh);
      if (lane < 32) s += wrow[256 + lane] * s_h[e * 256 + 224 + lane];
      s = wred(s);
      if (!lane) cstore(&g_oute[q], s + p.xb3[q]);
    }
  }
  if (W < 122) {
    const float* wrow = s_w7[wvin][1];
    float4 w = *(const float4*)(wrow + 4 * lane);
    int q = W + 250, e = q / 62;
    float4 xh = make_float4(0.f, 0.f, 0.f, 0.f);
    if (lane < 8) xh = *(const float4*)(s_zp + 4 * lane);
    else          xh = *(const float4*)(s_h + e * 256 + 4 * lane - 32);
    float s = dot4(w, xh);
    if (lane < 32) s += wrow[256 + lane] * s_h[e * 256 + 224 + lane];
    s = wred(s);
    if (!lane) cstore(&g_oute[q], s + p.xb3[q]);
  }
  gridbar(flags, 4);

  // ================= S8: decoded (WG0, parallel sc1 reads) ================
  if (blockIdx.x == 0) {
    s_o[tid] = cload(&g_oute[tid]);
    if (tid < 116) s_o[tid + 256] = cload(&g_oute[tid + 256]);
    if (tid < 6)   s_gg[tid] = cload(&g_gates[tid]);
    __syncthreads();
    if (tid < 62) {
      float s = 0.f;
#pragma unroll
      for (int e = 0; e < 6; ++e) s += s_o[e * 62 + tid] * s_gg[e];
      p.out[tid] = s;
    }
  }
}

extern "C" void kernel_launch(void* const* d_in, const int* in_sizes, int n_in,
                              void* d_out, int out_size, void* d_ws, size_t ws_size,
                              hipStream_t stream) {
  (void)in_sizes; (void)n_in; (void)out_size; (void)ws_size;
  const float* const* in = (const float* const*)d_in;
  P p;
  p.prev = in[0];  p.curr = in[1];  p.eps = in[2];
  p.ew0 = in[3];   p.eb0 = in[4];   p.ew1 = in[5];  p.eb1 = in[6];
  p.ew2 = in[7];   p.eb2 = in[8];
  p.muw = in[9];   p.mub = in[10];  p.lvw = in[11]; p.lvb = in[12];
  p.gw0 = in[13];  p.gb0 = in[14];  p.gw1 = in[15]; p.gb1 = in[16];
  p.gw2 = in[17];  p.gb2 = in[18];  p.gw3 = in[19]; p.gb3 = in[20];
  p.xw0 = in[21];  p.xb0 = in[22];  p.xw1 = in[23]; p.xb1 = in[24];
  p.xw2 = in[25];  p.xb2 = in[26];  p.xw3 = in[27]; p.xb3 = in[28];
  p.out = (float*)d_out;

  int* flags = (int*)d_ws;                        // 64 WGs x 1 cacheline
  hipMemsetAsync(flags, 0, NWG * 16 * sizeof(int), stream);
  mvae_main<<<NWG, BLOCK, 0, stream>>>(p, flags);
}